// Round 8
// baseline (249.823 us; speedup 1.0000x reference)
//
#include <hip/hip_runtime.h>

#define K  100   // NUM_BREAKPOINTS
#define NB 1024  // LUT buckets (power of 2 -> exact fp bucket math)

typedef float fvec4 __attribute__((ext_vector_type(4)));

// ---------------------------------------------------------------------------
// rd8: rd5's batched-gather loop (8 elements/iter, all 8 ds_read_b64 issued
// into DISTINCT registers, one dirty-branch per 8, depth-2 global prefetch)
// but with __launch_bounds__(256,4) -> 128-VGPR budget. rd7 revealed the rd0
// loop compiles to VGPR_Count=16, which forces the allocator to serialize
// the 4 LDS gathers (~500cyc serial latency/iter); rd5's (256,8) bound had
// the same disease at 24 VGPR. This is the first run where batched gathers
// get enough registers to actually stay in flight together.
//
// ws layout: [0,8192)      float2 bab[NB]
//            [8192,8592)   f32 sx[K]
//            [8704,9504)   float2 ab[K]
// ---------------------------------------------------------------------------
__global__ __launch_bounds__(1024) void pwl_setup_kernel(
    const float* __restrict__ xp, const float* __restrict__ sl,
    const float* __restrict__ bias, float2* __restrict__ bab_g,
    float* __restrict__ sx_g, float2* __restrict__ ab_g) {
  __shared__ float s_pos[K];
  __shared__ float s_slope[K];
  __shared__ float s_x[K];    // sorted breakpoints
  __shared__ float s_c[K];    // scan scratch
  __shared__ float s_sa[K];   // per-segment slope
  __shared__ float s_sb[K];   // per-segment intercept
  __shared__ unsigned short s_cnt[NB + 1];
  const int t = threadIdx.x;

  if (t < K) { s_pos[t] = xp[t]; s_slope[t] = sl[t]; }
  __syncthreads();

  // O(K^2) stable rank sort (ties broken by original index)
  if (t < K) {
    float v = s_pos[t];
    int r = 0;
    for (int j = 0; j < K; ++j) {
      float u = s_pos[j];
      r += ((u < v) || (u == v && j < t)) ? 1 : 0;
    }
    s_x[r] = v;
  }
  __syncthreads();

  // contributions c[i] = (sx[i+1]-sx[i]) * slope[i]
  if (t < K - 1) s_c[t] = (s_x[t + 1] - s_x[t]) * s_slope[t];
  __syncthreads();
  // Hillis-Steele inclusive scan (7 rounds)
  for (int off = 1; off < K - 1; off <<= 1) {
    float v = 0.0f;
    if (t >= off && t < K - 1) v = s_c[t - off];
    __syncthreads();
    if (t < K - 1) s_c[t] += v;
    __syncthreads();
  }
  // beta[i] = bias + cum[i-1]; fold to y = a*x + (beta - sx*a)
  if (t < K) {
    float beta = bias[0] + (t ? s_c[t - 1] : 0.0f);
    float a = s_slope[t];
    s_sa[t] = a;
    s_sb[t] = beta - s_x[t] * a;
  }
  __syncthreads();

  if (t < K) {
    sx_g[t] = s_x[t];
    ab_g[t] = make_float2(s_sa[t], s_sb[t]);
  }

  // cnt[e] = #breakpoints <= e/NB, via binary upper_bound
  for (int e = t; e <= NB; e += blockDim.x) {
    float ev = (float)e * (1.0f / (float)NB);  // exact (pow2 scale)
    int lo = 0, hi = K;
    while (lo < hi) {
      int mid = (lo + hi) >> 1;
      if (s_x[mid] <= ev) lo = mid + 1; else hi = mid;
    }
    s_cnt[e] = (unsigned short)lo;
  }
  __syncthreads();

  // direct bucket table (AoS float2)
  for (int b = t; b < NB; b += blockDim.x) {
    int lo = s_cnt[b], hi = s_cnt[b + 1];
    float2 e;
    if (lo == hi) {                      // clean: segment fully determined
      int idx = min(max(lo, 1), K) - 1;  // clip(cnt,1,K)-1
      e = make_float2(s_sa[idx], s_sb[idx]);
    } else {                             // dirty: marker + packed search range
      e.x = __builtin_huge_valf();
      e.y = __uint_as_float((unsigned)lo | ((unsigned)hi << 16));
    }
    bab_g[b] = e;
  }
}

// ---------------------------------------------------------------------------
// Main streaming kernel.
// ---------------------------------------------------------------------------
__global__ __launch_bounds__(256, 4) void pwl_main_kernel(
    const fvec4* __restrict__ x, const float2* __restrict__ bab_g,
    const float* __restrict__ sx_g, const float2* __restrict__ ab_g,
    fvec4* __restrict__ out, int n4, int n) {
  __shared__ float2 s_bab[NB];
  __shared__ float s_x[K];
  __shared__ float2 s_ab[K];
  for (int i = threadIdx.x; i < NB; i += blockDim.x) s_bab[i] = bab_g[i];
  if (threadIdx.x < K) {
    s_x[threadIdx.x] = sx_g[threadIdx.x];
    s_ab[threadIdx.x] = ab_g[threadIdx.x];
  }
  __syncthreads();

  const int stride = gridDim.x * blockDim.x;
  int i0 = blockIdx.x * blockDim.x + threadIdx.x;
  int i1 = i0 + stride;
  bool h0 = i0 < n4;
  bool h1 = i1 < n4;
  fvec4 v0 = {}, v1 = {};
  if (h0) v0 = x[i0];
  if (h1) v1 = x[i1];

  while (h0) {
    int j0 = i0 + 2 * stride;
    int j1 = i1 + 2 * stride;
    bool g0 = j0 < n4;
    bool g1 = j1 < n4;
    fvec4 w0 = {}, w1 = {};
    if (g0) w0 = x[j0];
    if (g1) w1 = x[j1];

    // ---- 8 elements: batch bucket computes, then 8 ds_read_b64 in flight ----
    float xe[8];
    xe[0] = v0.x; xe[1] = v0.y; xe[2] = v0.z; xe[3] = v0.w;
    xe[4] = v1.x; xe[5] = v1.y; xe[6] = v1.z; xe[7] = v1.w;

    float2 ab[8];
#pragma unroll
    for (int e = 0; e < 8; ++e) {
      int b = (int)(xe[e] * (float)NB);  // exact pow2 scale
      b = min(max(b, 0), NB - 1);
      ab[e] = s_bab[b];                  // independent b64 gathers, one drain
    }

    unsigned dirty = 0;
#pragma unroll
    for (int e = 0; e < 8; ++e)
      dirty |= (__float_as_uint(ab[e].x) == 0x7f800000u) ? (1u << e) : 0u;

    if (dirty) {  // rare-lane fixup, once per 8 elements
#pragma unroll
      for (int e = 0; e < 8; ++e) {
        if (dirty & (1u << e)) {
          unsigned p = __float_as_uint(ab[e].y);
          int lo = (int)(p & 0xffffu);
          int hi = (int)(p >> 16);
          while (lo < hi) {  // usually 1 iteration (hi-lo==1)
            int mid = (lo + hi) >> 1;
            if (s_x[mid] <= xe[e]) lo = mid + 1; else hi = mid;
          }
          int idx = min(max(lo, 1), K) - 1;
          ab[e] = s_ab[idx];
        }
      }
    }

    float y[8];
#pragma unroll
    for (int e = 0; e < 8; ++e)
      y[e] = fminf(fmaxf(fmaf(xe[e], ab[e].x, ab[e].y), 0.0f), 1.0f);

    fvec4 r0, r1;
    r0.x = y[0]; r0.y = y[1]; r0.z = y[2]; r0.w = y[3];
    r1.x = y[4]; r1.y = y[5]; r1.z = y[6]; r1.w = y[7];
    out[i0] = r0;
    if (h1) out[i1] = r1;

    i0 = j0; i1 = j1;
    v0 = w0; v1 = w1;
    h0 = g0; h1 = g1;
  }

  // scalar tail (n % 4), handled by block 0 (empty for this shape)
  if (blockIdx.x == 0) {
    const float* xs = (const float*)x;
    float* os = (float*)out;
    for (int j = (n4 << 2) + threadIdx.x; j < n; j += blockDim.x) {
      float xv = xs[j];
      int b = min(max((int)(xv * (float)NB), 0), NB - 1);
      float2 ab = s_bab[b];
      if (__float_as_uint(ab.x) == 0x7f800000u) {
        unsigned p = __float_as_uint(ab.y);
        int lo = (int)(p & 0xffffu);
        int hi = (int)(p >> 16);
        while (lo < hi) {
          int mid = (lo + hi) >> 1;
          if (s_x[mid] <= xv) lo = mid + 1; else hi = mid;
        }
        int idx = min(max(lo, 1), K) - 1;
        ab = s_ab[idx];
      }
      os[j] = fminf(fmaxf(fmaf(xv, ab.x, ab.y), 0.0f), 1.0f);
    }
  }
}

extern "C" void kernel_launch(void* const* d_in, const int* in_sizes, int n_in,
                              void* d_out, int out_size, void* d_ws, size_t ws_size,
                              hipStream_t stream) {
  const float* x    = (const float*)d_in[0];
  const float* xp   = (const float*)d_in[1];
  const float* sl   = (const float*)d_in[2];
  const float* bias = (const float*)d_in[3];
  float* out = (float*)d_out;

  float2* bab = (float2*)d_ws;                          // 8192 B
  float* sx   = (float*)((char*)d_ws + NB * 8);         // 400 B (+pad)
  float2* ab  = (float2*)((char*)d_ws + NB * 8 + 512);  // 800 B, 8B-aligned

  const int n  = in_sizes[0];
  const int n4 = n >> 2;

  pwl_setup_kernel<<<1, 1024, 0, stream>>>(xp, sl, bias, bab, sx, ab);

  const int threads = 256;
  const int blocks  = 2048;  // grid-stride; 4 blocks/CU resident (256,4)
  pwl_main_kernel<<<blocks, threads, 0, stream>>>(
      (const fvec4*)x, bab, sx, ab, (fvec4*)out, n4, n);
}